// Round 16
// baseline (348.598 us; speedup 1.0000x reference)
//
#include <hip/hip_runtime.h>
#include <cstdint>

typedef float f4 __attribute__((ext_vector_type(4)));
typedef short bf8 __attribute__((ext_vector_type(8)));
typedef unsigned int u32;
typedef unsigned int u32x4 __attribute__((ext_vector_type(4)));
typedef unsigned short u16;

// ---------------------------------------------------------------------------
// SNN: 64-step scan over 3 spike-gated linear layers.
// GEMM: EXACT-SPLIT bf16x3 (w = hi+mid+lo by truncation; exact). 3 planes
// chained in one f32 MFMA acc, flushed to f64 every K=32. absmax 0 since R12.
// R15: 2 SSA load sets, 3 waves/SIMD -> 203 µs. R16: in-block K-reduction —
// 4-wave blocks share one j-tile, take 4 different K-chunks, reduce f64
// accumulators via LDS (2 rounds), wave 0 writes ONE P slice. P traffic /4
// (200 -> 50 MB round-trip); occupancy unchanged (3 blocks/CU, 32 KB LDS).
// ---------------------------------------------------------------------------

__device__ __forceinline__ float uf(u32 x) { return __builtin_bit_cast(float, x); }
__device__ __forceinline__ u32 fu(float x) { return __builtin_bit_cast(u32, x); }

struct FragMap { int amode, bmode, rw[4], cl[4]; };

// Inline layout probe (proven R12-R15): 2 MFMAs with ones/lane-id operands
// decode C/D coords (rw/cl) and A/B lane modes.
// d1[m][n] = 8*sum_k B[k][n]: mode0 (n=lane&15) -> 32n+768; mode1 -> 128n+48.
__device__ __forceinline__ FragMap probe_map()
{
    int l = threadIdx.x & 63;
    u32 lb = fu((float)l) >> 16;            // exact bf16 of lane id (l<=63)
    u32 lbb = lb | (lb << 16);
    u32x4 lv4 = {lbb, lbb, lbb, lbb};
    u32x4 on4 = {0x3F803F80u, 0x3F803F80u, 0x3F803F80u, 0x3F803F80u};
    bf8 lv = __builtin_bit_cast(bf8, lv4);
    bf8 on = __builtin_bit_cast(bf8, on4);
    f4 z = {0.f, 0.f, 0.f, 0.f};
    f4 d1 = __builtin_amdgcn_mfma_f32_16x16x32_bf16(on, lv, z, 0, 0, 0);
    f4 d2 = __builtin_amdgcn_mfma_f32_16x16x32_bf16(lv, on, z, 0, 0, 0);
    FragMap fm; fm.amode = 0; fm.bmode = 0;
#pragma unroll
    for (int r = 0; r < 4; ++r) {
        int v1 = (int)(d1[r] + 0.5f);
        if (v1 >= 768 && v1 <= 1248 && ((v1 - 768) & 31) == 0) { fm.cl[r] = (v1 - 768) >> 5; fm.bmode = 0; }
        else                                                   { fm.cl[r] = (v1 - 48) >> 7;  fm.bmode = 1; }
        int v2 = (int)(d2[r] + 0.5f);
        if (v2 >= 768 && v2 <= 1248 && ((v2 - 768) & 31) == 0) { fm.rw[r] = (v2 - 768) >> 5; fm.amode = 0; }
        else                                                   { fm.rw[r] = (v2 - 48) >> 7;  fm.amode = 1; }
    }
    return fm;
}

// Spike fragment store: SA[i>>5][tt=t>>4][lane][e]; writer lane from amode,
// e = i&7, g = (i&31)>>3 -> lane holding A row m=(t&15), k-group g.
__global__ __launch_bounds__(256) void k_input(const float* __restrict__ img,
                                               float* __restrict__ out0, // 65 x n
                                               u16* __restrict__ SA0, int n)
{
    FragMap fm = probe_map();
    int i = blockIdx.x * 256 + threadIdx.x;
    if (i >= n) return;
    int g = (i & 31) >> 3, e = i & 7;
    int lanes[16];
#pragma unroll
    for (int m = 0; m < 16; ++m) lanes[m] = (fm.amode == 0) ? (g * 16 + m) : (m * 4 + g);
    u16* base = SA0 + ((size_t)(i >> 5)) * 2048 + e;
    double m = 0.0;
    double x = (double)img[i];
#pragma unroll
    for (int t = 0; t < 64; ++t) {
        m += x;
        bool fire = (m >= 1.0);
        if (fire) m -= 1.0;          // input layer: no decay
        out0[(size_t)t * n + i] = fire ? 1.0f : 0.0f;
        base[((t >> 4) << 9) + (lanes[t & 15] << 3)] = fire ? (u16)0x3F80 : (u16)0;
    }
    out0[(size_t)64 * n + i] = 0.0f; // pad_tail: last row zero
}

// split 2 f32 (even,odd k) -> packed bf16 dwords for hi/mid/lo planes (exact)
#define SPLIT2(we, wo, hD, mD, lD) do {                                        \
    u32 he = (we) & 0xFFFF0000u; float r1e = uf(we) - uf(he);                  \
    u32 me = fu(r1e) & 0xFFFF0000u; float r2e = r1e - uf(me); u32 le = fu(r2e);\
    u32 ho = (wo) & 0xFFFF0000u; float r1o = uf(wo) - uf(ho);                  \
    u32 mo = fu(r1o) & 0xFFFF0000u; float r2o = r1o - uf(mo); u32 lo2 = fu(r2o);\
    hD = (he >> 16) | ho; mD = (me >> 16) | mo;                                \
    lD = (le >> 16) | (lo2 & 0xFFFF0000u);                                     \
} while (0)

// bf16x3 spike-gated GEMM partials with in-block K-reduction:
// P[bc][t][j] = sum over the block's 4 wave-chunks (c = bc*4+wv).
// Grid (n_out/32, CB); block = 4 waves sharing one j-tile; K-step = 32.
// 2 SSA load sets; LDS f64 reduce (2 rounds); wave 0 writes P.
template<int NOUT>
__global__ __launch_bounds__(256, 3) void k_gemm(const float* __restrict__ W,
                                                 const u16* __restrict__ SA,
                                                 double* __restrict__ P,
                                                 int n_in, int ipc)
{
    FragMap fm = probe_map();
    const int lane = threadIdx.x & 63;
    const int wv   = threadIdx.x >> 6;
    const int j0   = blockIdx.x * 32;
    const int c    = blockIdx.y * 4 + wv;
    const int gB   = (fm.bmode == 0) ? (lane >> 4) : (lane & 3);
    const int nB   = (fm.bmode == 0) ? (lane & 15) : (lane >> 2);

    int i0 = c * ipc;
    int i1 = i0 + ipc; if (i1 > n_in) i1 = n_in;
    int nsteps = (i1 > i0) ? ((i1 - i0) >> 5) : 0;   // 32 i's per step

    double accd[2][4][4];
#pragma unroll
    for (int jt = 0; jt < 2; ++jt)
#pragma unroll
        for (int tt = 0; tt < 4; ++tt)
#pragma unroll
            for (int r = 0; r < 4; ++r) accd[jt][tt][r] = 0.0;

    const size_t wstep = (size_t)32 * NOUT;
    struct Set { const u32* wp; const u16* ap; u32 w[16]; u32x4 a[4]; };
    Set S0_, S1_;
    S0_.wp = (const u32*)W + (size_t)(i0 + gB * 8) * NOUT + j0 + nB;
    S1_.wp = S0_.wp + wstep;
    S0_.ap = SA + (size_t)(i0 >> 5) * 2048 + lane * 8;
    S1_.ap = S0_.ap + 2048;

#define LOADSET(S, sidx) do {                                                  \
        if ((sidx) < nsteps) {                                                 \
            _Pragma("unroll") for (int k = 0; k < 8; ++k) {                    \
                S.w[k]     = S.wp[(size_t)k * NOUT];                           \
                S.w[8 + k] = S.wp[(size_t)k * NOUT + 16];                      \
            }                                                                  \
            _Pragma("unroll") for (int tt = 0; tt < 4; ++tt)                   \
                S.a[tt] = *(const u32x4*)(S.ap + tt * 512);                    \
        } else {                                                               \
            _Pragma("unroll") for (int k = 0; k < 16; ++k) S.w[k] = 0;         \
            _Pragma("unroll") for (int tt = 0; tt < 4; ++tt)                   \
                S.a[tt] = (u32x4){0, 0, 0, 0};                                 \
        }                                                                      \
        S.wp += 2 * wstep; S.ap += 4096;                                       \
    } while (0)

#define COMPUTESET(S) do {                                                     \
        _Pragma("unroll") for (int jt = 0; jt < 2; ++jt) {                     \
            u32 hd[4], md[4], ld[4];                                           \
            _Pragma("unroll") for (int p = 0; p < 4; ++p)                      \
                SPLIT2(S.w[jt * 8 + 2 * p], S.w[jt * 8 + 2 * p + 1],           \
                       hd[p], md[p], ld[p]);                                   \
            u32x4 hv = {hd[0], hd[1], hd[2], hd[3]};                           \
            u32x4 mv = {md[0], md[1], md[2], md[3]};                           \
            u32x4 lv = {ld[0], ld[1], ld[2], ld[3]};                           \
            bf8 Bh = __builtin_bit_cast(bf8, hv);                              \
            bf8 Bm = __builtin_bit_cast(bf8, mv);                              \
            bf8 Bl = __builtin_bit_cast(bf8, lv);                              \
            f4 zz = {0.f, 0.f, 0.f, 0.f};                                      \
            _Pragma("unroll") for (int tt = 0; tt < 4; ++tt) {                 \
                bf8 Af = __builtin_bit_cast(bf8, S.a[tt]);                     \
                f4 acc = __builtin_amdgcn_mfma_f32_16x16x32_bf16(Af, Bh, zz, 0, 0, 0); \
                acc = __builtin_amdgcn_mfma_f32_16x16x32_bf16(Af, Bm, acc, 0, 0, 0);   \
                acc = __builtin_amdgcn_mfma_f32_16x16x32_bf16(Af, Bl, acc, 0, 0, 0);   \
                _Pragma("unroll") for (int r = 0; r < 4; ++r)                  \
                    accd[jt][tt][r] += (double)acc[r];                         \
            }                                                                  \
        }                                                                      \
    } while (0)

    LOADSET(S0_, 0);
    LOADSET(S1_, 1);

    int rounds = (nsteps + 1) / 2;
    int s = 0;
    for (int r = 0; r < rounds; ++r) {
        COMPUTESET(S0_); LOADSET(S0_, s + 2);   // consumed 1 compute-step later
        COMPUTESET(S1_); LOADSET(S1_, s + 3);
        s += 2;
    }
#undef LOADSET
#undef COMPUTESET

    // In-block f64 reduction across the 4 wave-chunks: order ((c0+c2)+(c1+c3)).
    // lds[s][k][lane]: lane-contiguous -> conflict-free. 32 KB.
    __shared__ double lds[2][32][64];
    if (wv >= 2) {
#pragma unroll
        for (int jt = 0; jt < 2; ++jt)
#pragma unroll
            for (int tt = 0; tt < 4; ++tt)
#pragma unroll
                for (int r = 0; r < 4; ++r)
                    lds[wv - 2][jt * 16 + tt * 4 + r][lane] = accd[jt][tt][r];
    }
    __syncthreads();
    if (wv < 2) {
#pragma unroll
        for (int jt = 0; jt < 2; ++jt)
#pragma unroll
            for (int tt = 0; tt < 4; ++tt)
#pragma unroll
                for (int r = 0; r < 4; ++r)
                    accd[jt][tt][r] += lds[wv][jt * 16 + tt * 4 + r][lane];
    }
    __syncthreads();
    if (wv == 1) {
#pragma unroll
        for (int jt = 0; jt < 2; ++jt)
#pragma unroll
            for (int tt = 0; tt < 4; ++tt)
#pragma unroll
                for (int r = 0; r < 4; ++r)
                    lds[0][jt * 16 + tt * 4 + r][lane] = accd[jt][tt][r];
    }
    __syncthreads();
    if (wv == 0) {
        double* pc = P + (size_t)blockIdx.y * 64 * NOUT;
#pragma unroll
        for (int jt = 0; jt < 2; ++jt)
#pragma unroll
            for (int tt = 0; tt < 4; ++tt)
#pragma unroll
                for (int r = 0; r < 4; ++r) {
                    double v = accd[jt][tt][r] + lds[0][jt * 16 + tt * 4 + r][lane];
                    pc[(size_t)(tt * 16 + fm.rw[r]) * NOUT + (j0 + jt * 16 + fm.cl[r])] = v;
                }
    }
}

// U[t][j] = sum over block-chunks bc of P[bc][t][j]  (fixed order)
__global__ __launch_bounds__(256) void k_reduceU(const double* __restrict__ P,
                                                 double* __restrict__ U,
                                                 int nchunks, int n_out)
{
    int gid = blockIdx.x * 256 + threadIdx.x;
    int total = 64 * n_out;
    if (gid >= total) return;
    int t = gid / n_out;
    int j = gid - t * n_out;
    double s = 0.0;
    for (int c = 0; c < nchunks; ++c)
        s += P[((size_t)c * 64 + t) * n_out + j];
    U[gid] = s;
}

// Per-neuron membrane scan; emits next layer's bf16 spike fragments.
__global__ __launch_bounds__(256) void k_scan(const double* __restrict__ U,
                                              float* __restrict__ outS, // 65 x n_out
                                              u16* __restrict__ SAn,    // may be null
                                              int n_out, int shift)
{
    FragMap fm = probe_map();
    int j = blockIdx.x * 256 + threadIdx.x;
    if (j >= n_out) return;
    int g = (j & 31) >> 3, e = j & 7;
    int lanes[16];
#pragma unroll
    for (int m = 0; m < 16; ++m) lanes[m] = (fm.amode == 0) ? (g * 16 + m) : (m * 4 + g);
    u16* base = SAn ? (SAn + ((size_t)(j >> 5)) * 2048 + e) : (u16*)nullptr;
    double m = 0.0;
    outS[j] = 0.0f;                           // row 0 zero (pad_head)
#pragma unroll
    for (int t = 0; t < 64; ++t) {
        int s = t - shift;
        double u = (s >= 0) ? U[(size_t)s * n_out + j] : 0.0;
        m += u;
        bool fire = (m >= 1.0);
        m = fire ? (m - 1.0) : (m * 0.5);
        outS[(size_t)(t + 1) * n_out + j] = fire ? 1.0f : 0.0f;
        if (base) base[((t >> 4) << 9) + (lanes[t & 15] << 3)] = fire ? (u16)0x3F80 : (u16)0;
    }
}

extern "C" void kernel_launch(void* const* d_in, const int* in_sizes, int n_in_cnt,
                              void* d_out, int out_size, void* d_ws, size_t ws_size,
                              hipStream_t stream)
{
    const float* img = (const float*)d_in[0];
    const float* w1  = (const float*)d_in[1];
    const float* w2  = (const float*)d_in[2];
    const float* w3  = (const float*)d_in[3];

    const int N0 = 16384, N1 = 4096, N2 = 4096, N3 = 1024;

    float* out0 = (float*)d_out;
    float* out1 = out0 + (size_t)65 * N0;
    float* out2 = out1 + (size_t)65 * N1;
    float* out3 = out2 + (size_t)65 * N2;

    // workspace layout
    char* ws = (char*)d_ws;
    const size_t MB = 1024 * 1024;
    u16*    SA0 = (u16*)(ws);                     // 16384*64*2 = 2 MiB
    u16*    SA1 = (u16*)(ws + 2 * MB);            // 512 KiB
    u16*    SA2 = (u16*)(ws + 2 * MB + 512 * 1024);
    double* U   = (double*)(ws + 3 * MB);         // 2 MiB
    double* P   = (double*)(ws + 5 * MB);

    size_t fixed = 5 * MB;
    size_t pbudget = (ws_size > fixed) ? (ws_size - fixed) : 0;

    // P bytes per block-chunk = 64 t x n_out x 8B = 512*n_out
    auto clampi = [](long v, int lo, int hi) { int x = (int)v; if (x < lo) x = lo; if (x > hi) x = hi; return x; };
    int CB1 = clampi((long)(pbudget / (512ull * N1)), 1, 6);  // 128x6 = 768 blocks = 3/CU
    int CB2 = clampi((long)(pbudget / (512ull * N2)), 1, 4);  // 512 blocks
    int CB3 = clampi((long)(pbudget / (512ull * N3)), 1, 8);  // 256 blocks
    int C1 = CB1 * 4, C2 = CB2 * 4, C3 = CB3 * 4;

    auto ipc32 = [](int n_in, int C) { return (((n_in + C - 1) / C) + 31) & ~31; };

    // layer 0 (input): spikes + bf16 fragment-layout S0
    k_input<<<N0 / 256, 256, 0, stream>>>(img, out0, SA0, N0);

    // layer 1: U1 = S0 @ W1 (same-step spikes)
    k_gemm<4096><<<dim3(N1 / 32, CB1), 256, 0, stream>>>(w1, SA0, P, N0, ipc32(N0, C1));
    k_reduceU<<<(64 * N1) / 256, 256, 0, stream>>>(P, U, CB1, N1);
    k_scan<<<N1 / 256, 256, 0, stream>>>(U, out1, SA1, N1, 0);

    // layer 2: uses previous-step s1
    k_gemm<4096><<<dim3(N2 / 32, CB2), 256, 0, stream>>>(w2, SA1, P, N1, ipc32(N1, C2));
    k_reduceU<<<(64 * N2) / 256, 256, 0, stream>>>(P, U, CB2, N2);
    k_scan<<<N2 / 256, 256, 0, stream>>>(U, out2, SA2, N2, 1);

    // layer 3: uses previous-step s2
    k_gemm<1024><<<dim3(N3 / 32, CB3), 256, 0, stream>>>(w3, SA2, P, N2, ipc32(N2, C3));
    k_reduceU<<<(64 * N3) / 256, 256, 0, stream>>>(P, U, CB3, N3);
    k_scan<<<N3 / 256, 256, 0, stream>>>(U, out3, (u16*)nullptr, N3, 1);
}

// Round 17
// 183.417 us; speedup vs baseline: 1.9006x; 1.9006x over previous
//
#include <hip/hip_runtime.h>
#include <cstdint>

typedef float f4 __attribute__((ext_vector_type(4)));
typedef short bf8 __attribute__((ext_vector_type(8)));
typedef unsigned int u32;
typedef unsigned int u32x4 __attribute__((ext_vector_type(4)));
typedef unsigned short u16;

// ---------------------------------------------------------------------------
// SNN: 64-step scan over 3 spike-gated linear layers.
// GEMM: EXACT-SPLIT bf16x3 (w = hi+mid+lo by truncation; exact). 3 planes
// chained in one f32 MFMA acc, flushed to f64 every K=32. absmax 0 since R12.
// R16 lesson: __launch_bounds__(256,3) capped regs at ~170 -> spill (VGPR 84
// + AGPR 84 = cap; FETCH +50MB scratch; MfmaUtil 4.7%). R17: SAME kernel with
// (256,2) -> cap 256, no spill, 2 waves/SIMD (R15's effective residency).
// In-block K-reduction now pays: P traffic /4 vs R15. Grid tuned to the
// 2-waves/SIMD quantum: CB1=CB2=8 (1024 blocks x 4 waves = 4096 = 2/SIMD).
// ---------------------------------------------------------------------------

__device__ __forceinline__ float uf(u32 x) { return __builtin_bit_cast(float, x); }
__device__ __forceinline__ u32 fu(float x) { return __builtin_bit_cast(u32, x); }

struct FragMap { int amode, bmode, rw[4], cl[4]; };

// Inline layout probe (proven R12-R16): 2 MFMAs with ones/lane-id operands
// decode C/D coords (rw/cl) and A/B lane modes.
// d1[m][n] = 8*sum_k B[k][n]: mode0 (n=lane&15) -> 32n+768; mode1 -> 128n+48.
__device__ __forceinline__ FragMap probe_map()
{
    int l = threadIdx.x & 63;
    u32 lb = fu((float)l) >> 16;            // exact bf16 of lane id (l<=63)
    u32 lbb = lb | (lb << 16);
    u32x4 lv4 = {lbb, lbb, lbb, lbb};
    u32x4 on4 = {0x3F803F80u, 0x3F803F80u, 0x3F803F80u, 0x3F803F80u};
    bf8 lv = __builtin_bit_cast(bf8, lv4);
    bf8 on = __builtin_bit_cast(bf8, on4);
    f4 z = {0.f, 0.f, 0.f, 0.f};
    f4 d1 = __builtin_amdgcn_mfma_f32_16x16x32_bf16(on, lv, z, 0, 0, 0);
    f4 d2 = __builtin_amdgcn_mfma_f32_16x16x32_bf16(lv, on, z, 0, 0, 0);
    FragMap fm; fm.amode = 0; fm.bmode = 0;
#pragma unroll
    for (int r = 0; r < 4; ++r) {
        int v1 = (int)(d1[r] + 0.5f);
        if (v1 >= 768 && v1 <= 1248 && ((v1 - 768) & 31) == 0) { fm.cl[r] = (v1 - 768) >> 5; fm.bmode = 0; }
        else                                                   { fm.cl[r] = (v1 - 48) >> 7;  fm.bmode = 1; }
        int v2 = (int)(d2[r] + 0.5f);
        if (v2 >= 768 && v2 <= 1248 && ((v2 - 768) & 31) == 0) { fm.rw[r] = (v2 - 768) >> 5; fm.amode = 0; }
        else                                                   { fm.rw[r] = (v2 - 48) >> 7;  fm.amode = 1; }
    }
    return fm;
}

// Spike fragment store: SA[i>>5][tt=t>>4][lane][e]; writer lane from amode,
// e = i&7, g = (i&31)>>3 -> lane holding A row m=(t&15), k-group g.
__global__ __launch_bounds__(256) void k_input(const float* __restrict__ img,
                                               float* __restrict__ out0, // 65 x n
                                               u16* __restrict__ SA0, int n)
{
    FragMap fm = probe_map();
    int i = blockIdx.x * 256 + threadIdx.x;
    if (i >= n) return;
    int g = (i & 31) >> 3, e = i & 7;
    int lanes[16];
#pragma unroll
    for (int m = 0; m < 16; ++m) lanes[m] = (fm.amode == 0) ? (g * 16 + m) : (m * 4 + g);
    u16* base = SA0 + ((size_t)(i >> 5)) * 2048 + e;
    double m = 0.0;
    double x = (double)img[i];
#pragma unroll
    for (int t = 0; t < 64; ++t) {
        m += x;
        bool fire = (m >= 1.0);
        if (fire) m -= 1.0;          // input layer: no decay
        out0[(size_t)t * n + i] = fire ? 1.0f : 0.0f;
        base[((t >> 4) << 9) + (lanes[t & 15] << 3)] = fire ? (u16)0x3F80 : (u16)0;
    }
    out0[(size_t)64 * n + i] = 0.0f; // pad_tail: last row zero
}

// split 2 f32 (even,odd k) -> packed bf16 dwords for hi/mid/lo planes (exact)
#define SPLIT2(we, wo, hD, mD, lD) do {                                        \
    u32 he = (we) & 0xFFFF0000u; float r1e = uf(we) - uf(he);                  \
    u32 me = fu(r1e) & 0xFFFF0000u; float r2e = r1e - uf(me); u32 le = fu(r2e);\
    u32 ho = (wo) & 0xFFFF0000u; float r1o = uf(wo) - uf(ho);                  \
    u32 mo = fu(r1o) & 0xFFFF0000u; float r2o = r1o - uf(mo); u32 lo2 = fu(r2o);\
    hD = (he >> 16) | ho; mD = (me >> 16) | mo;                                \
    lD = (le >> 16) | (lo2 & 0xFFFF0000u);                                     \
} while (0)

// bf16x3 spike-gated GEMM partials with in-block K-reduction:
// P[bc][t][j] = sum over the block's 4 wave-chunks (c = bc*4+wv).
// Grid (n_out/32, CB); block = 4 waves sharing one j-tile; K-step = 32.
// 2 SSA load sets; LDS f64 reduce (2 rounds); wave 0 writes P.
template<int NOUT>
__global__ __launch_bounds__(256, 2) void k_gemm(const float* __restrict__ W,
                                                 const u16* __restrict__ SA,
                                                 double* __restrict__ P,
                                                 int n_in, int ipc)
{
    FragMap fm = probe_map();
    const int lane = threadIdx.x & 63;
    const int wv   = threadIdx.x >> 6;
    const int j0   = blockIdx.x * 32;
    const int c    = blockIdx.y * 4 + wv;
    const int gB   = (fm.bmode == 0) ? (lane >> 4) : (lane & 3);
    const int nB   = (fm.bmode == 0) ? (lane & 15) : (lane >> 2);

    int i0 = c * ipc;
    int i1 = i0 + ipc; if (i1 > n_in) i1 = n_in;
    int nsteps = (i1 > i0) ? ((i1 - i0) >> 5) : 0;   // 32 i's per step

    double accd[2][4][4];
#pragma unroll
    for (int jt = 0; jt < 2; ++jt)
#pragma unroll
        for (int tt = 0; tt < 4; ++tt)
#pragma unroll
            for (int r = 0; r < 4; ++r) accd[jt][tt][r] = 0.0;

    const size_t wstep = (size_t)32 * NOUT;
    struct Set { const u32* wp; const u16* ap; u32 w[16]; u32x4 a[4]; };
    Set S0_, S1_;
    S0_.wp = (const u32*)W + (size_t)(i0 + gB * 8) * NOUT + j0 + nB;
    S1_.wp = S0_.wp + wstep;
    S0_.ap = SA + (size_t)(i0 >> 5) * 2048 + lane * 8;
    S1_.ap = S0_.ap + 2048;

#define LOADSET(S, sidx) do {                                                  \
        if ((sidx) < nsteps) {                                                 \
            _Pragma("unroll") for (int k = 0; k < 8; ++k) {                    \
                S.w[k]     = S.wp[(size_t)k * NOUT];                           \
                S.w[8 + k] = S.wp[(size_t)k * NOUT + 16];                      \
            }                                                                  \
            _Pragma("unroll") for (int tt = 0; tt < 4; ++tt)                   \
                S.a[tt] = *(const u32x4*)(S.ap + tt * 512);                    \
        } else {                                                               \
            _Pragma("unroll") for (int k = 0; k < 16; ++k) S.w[k] = 0;         \
            _Pragma("unroll") for (int tt = 0; tt < 4; ++tt)                   \
                S.a[tt] = (u32x4){0, 0, 0, 0};                                 \
        }                                                                      \
        S.wp += 2 * wstep; S.ap += 4096;                                       \
    } while (0)

#define COMPUTESET(S) do {                                                     \
        _Pragma("unroll") for (int jt = 0; jt < 2; ++jt) {                     \
            u32 hd[4], md[4], ld[4];                                           \
            _Pragma("unroll") for (int p = 0; p < 4; ++p)                      \
                SPLIT2(S.w[jt * 8 + 2 * p], S.w[jt * 8 + 2 * p + 1],           \
                       hd[p], md[p], ld[p]);                                   \
            u32x4 hv = {hd[0], hd[1], hd[2], hd[3]};                           \
            u32x4 mv = {md[0], md[1], md[2], md[3]};                           \
            u32x4 lv = {ld[0], ld[1], ld[2], ld[3]};                           \
            bf8 Bh = __builtin_bit_cast(bf8, hv);                              \
            bf8 Bm = __builtin_bit_cast(bf8, mv);                              \
            bf8 Bl = __builtin_bit_cast(bf8, lv);                              \
            f4 zz = {0.f, 0.f, 0.f, 0.f};                                      \
            _Pragma("unroll") for (int tt = 0; tt < 4; ++tt) {                 \
                bf8 Af = __builtin_bit_cast(bf8, S.a[tt]);                     \
                f4 acc = __builtin_amdgcn_mfma_f32_16x16x32_bf16(Af, Bh, zz, 0, 0, 0); \
                acc = __builtin_amdgcn_mfma_f32_16x16x32_bf16(Af, Bm, acc, 0, 0, 0);   \
                acc = __builtin_amdgcn_mfma_f32_16x16x32_bf16(Af, Bl, acc, 0, 0, 0);   \
                _Pragma("unroll") for (int r = 0; r < 4; ++r)                  \
                    accd[jt][tt][r] += (double)acc[r];                         \
            }                                                                  \
        }                                                                      \
    } while (0)

    LOADSET(S0_, 0);
    LOADSET(S1_, 1);

    int rounds = (nsteps + 1) / 2;
    int s = 0;
    for (int r = 0; r < rounds; ++r) {
        COMPUTESET(S0_); LOADSET(S0_, s + 2);   // consumed 1 compute-step later
        COMPUTESET(S1_); LOADSET(S1_, s + 3);
        s += 2;
    }
#undef LOADSET
#undef COMPUTESET

    // In-block f64 reduction across the 4 wave-chunks: order ((c0+c2)+(c1+c3)).
    // lds[s][k][lane]: lane-contiguous -> conflict-free. 32 KB.
    __shared__ double lds[2][32][64];
    if (wv >= 2) {
#pragma unroll
        for (int jt = 0; jt < 2; ++jt)
#pragma unroll
            for (int tt = 0; tt < 4; ++tt)
#pragma unroll
                for (int r = 0; r < 4; ++r)
                    lds[wv - 2][jt * 16 + tt * 4 + r][lane] = accd[jt][tt][r];
    }
    __syncthreads();
    if (wv < 2) {
#pragma unroll
        for (int jt = 0; jt < 2; ++jt)
#pragma unroll
            for (int tt = 0; tt < 4; ++tt)
#pragma unroll
                for (int r = 0; r < 4; ++r)
                    accd[jt][tt][r] += lds[wv][jt * 16 + tt * 4 + r][lane];
    }
    __syncthreads();
    if (wv == 1) {
#pragma unroll
        for (int jt = 0; jt < 2; ++jt)
#pragma unroll
            for (int tt = 0; tt < 4; ++tt)
#pragma unroll
                for (int r = 0; r < 4; ++r)
                    lds[0][jt * 16 + tt * 4 + r][lane] = accd[jt][tt][r];
    }
    __syncthreads();
    if (wv == 0) {
        double* pc = P + (size_t)blockIdx.y * 64 * NOUT;
#pragma unroll
        for (int jt = 0; jt < 2; ++jt)
#pragma unroll
            for (int tt = 0; tt < 4; ++tt)
#pragma unroll
                for (int r = 0; r < 4; ++r) {
                    double v = accd[jt][tt][r] + lds[0][jt * 16 + tt * 4 + r][lane];
                    pc[(size_t)(tt * 16 + fm.rw[r]) * NOUT + (j0 + jt * 16 + fm.cl[r])] = v;
                }
    }
}

// U[t][j] = sum over block-chunks bc of P[bc][t][j]  (fixed order)
__global__ __launch_bounds__(256) void k_reduceU(const double* __restrict__ P,
                                                 double* __restrict__ U,
                                                 int nchunks, int n_out)
{
    int gid = blockIdx.x * 256 + threadIdx.x;
    int total = 64 * n_out;
    if (gid >= total) return;
    int t = gid / n_out;
    int j = gid - t * n_out;
    double s = 0.0;
    for (int c = 0; c < nchunks; ++c)
        s += P[((size_t)c * 64 + t) * n_out + j];
    U[gid] = s;
}

// Per-neuron membrane scan; emits next layer's bf16 spike fragments.
__global__ __launch_bounds__(256) void k_scan(const double* __restrict__ U,
                                              float* __restrict__ outS, // 65 x n_out
                                              u16* __restrict__ SAn,    // may be null
                                              int n_out, int shift)
{
    FragMap fm = probe_map();
    int j = blockIdx.x * 256 + threadIdx.x;
    if (j >= n_out) return;
    int g = (j & 31) >> 3, e = j & 7;
    int lanes[16];
#pragma unroll
    for (int m = 0; m < 16; ++m) lanes[m] = (fm.amode == 0) ? (g * 16 + m) : (m * 4 + g);
    u16* base = SAn ? (SAn + ((size_t)(j >> 5)) * 2048 + e) : (u16*)nullptr;
    double m = 0.0;
    outS[j] = 0.0f;                           // row 0 zero (pad_head)
#pragma unroll
    for (int t = 0; t < 64; ++t) {
        int s = t - shift;
        double u = (s >= 0) ? U[(size_t)s * n_out + j] : 0.0;
        m += u;
        bool fire = (m >= 1.0);
        m = fire ? (m - 1.0) : (m * 0.5);
        outS[(size_t)(t + 1) * n_out + j] = fire ? 1.0f : 0.0f;
        if (base) base[((t >> 4) << 9) + (lanes[t & 15] << 3)] = fire ? (u16)0x3F80 : (u16)0;
    }
}

extern "C" void kernel_launch(void* const* d_in, const int* in_sizes, int n_in_cnt,
                              void* d_out, int out_size, void* d_ws, size_t ws_size,
                              hipStream_t stream)
{
    const float* img = (const float*)d_in[0];
    const float* w1  = (const float*)d_in[1];
    const float* w2  = (const float*)d_in[2];
    const float* w3  = (const float*)d_in[3];

    const int N0 = 16384, N1 = 4096, N2 = 4096, N3 = 1024;

    float* out0 = (float*)d_out;
    float* out1 = out0 + (size_t)65 * N0;
    float* out2 = out1 + (size_t)65 * N1;
    float* out3 = out2 + (size_t)65 * N2;

    // workspace layout
    char* ws = (char*)d_ws;
    const size_t MB = 1024 * 1024;
    u16*    SA0 = (u16*)(ws);                     // 16384*64*2 = 2 MiB
    u16*    SA1 = (u16*)(ws + 2 * MB);            // 512 KiB
    u16*    SA2 = (u16*)(ws + 2 * MB + 512 * 1024);
    double* U   = (double*)(ws + 3 * MB);         // 2 MiB
    double* P   = (double*)(ws + 5 * MB);

    size_t fixed = 5 * MB;
    size_t pbudget = (ws_size > fixed) ? (ws_size - fixed) : 0;

    // P bytes per block-chunk = 64 t x n_out x 8B = 512*n_out
    auto clampi = [](long v, int lo, int hi) { int x = (int)v; if (x < lo) x = lo; if (x > hi) x = hi; return x; };
    int CB1 = clampi((long)(pbudget / (512ull * N1)), 1, 8);   // 128x8 = 1024 blocks = 2 waves/SIMD
    int CB2 = clampi((long)(pbudget / (512ull * N2)), 1, 8);   // 1024 blocks
    int CB3 = clampi((long)(pbudget / (512ull * N3)), 1, 16);  // 512 blocks
    int C1 = CB1 * 4, C2 = CB2 * 4, C3 = CB3 * 4;

    auto ipc32 = [](int n_in, int C) { return (((n_in + C - 1) / C) + 31) & ~31; };

    // layer 0 (input): spikes + bf16 fragment-layout S0
    k_input<<<N0 / 256, 256, 0, stream>>>(img, out0, SA0, N0);

    // layer 1: U1 = S0 @ W1 (same-step spikes)
    k_gemm<4096><<<dim3(N1 / 32, CB1), 256, 0, stream>>>(w1, SA0, P, N0, ipc32(N0, C1));
    k_reduceU<<<(64 * N1) / 256, 256, 0, stream>>>(P, U, CB1, N1);
    k_scan<<<N1 / 256, 256, 0, stream>>>(U, out1, SA1, N1, 0);

    // layer 2: uses previous-step s1
    k_gemm<4096><<<dim3(N2 / 32, CB2), 256, 0, stream>>>(w2, SA1, P, N1, ipc32(N1, C2));
    k_reduceU<<<(64 * N2) / 256, 256, 0, stream>>>(P, U, CB2, N2);
    k_scan<<<N2 / 256, 256, 0, stream>>>(U, out2, SA2, N2, 1);

    // layer 3: uses previous-step s2
    k_gemm<1024><<<dim3(N3 / 32, CB3), 256, 0, stream>>>(w3, SA2, P, N2, ipc32(N2, C3));
    k_reduceU<<<(64 * N3) / 256, 256, 0, stream>>>(P, U, CB3, N3);
    k_scan<<<N3 / 256, 256, 0, stream>>>(U, out3, (u16*)nullptr, N3, 1);
}